// Round 3
// baseline (589.715 us; speedup 1.0000x reference)
//
#include <hip/hip_runtime.h>

#define D 128
#define SB 256
#define BSH 6                    // bucket = dst >> BSH  (64 nodes per bucket)
#define BNODES (1 << BSH)

__device__ __forceinline__ float bf2f(unsigned short u) {
    return __uint_as_float(((unsigned int)u) << 16);
}
__device__ __forceinline__ unsigned short f2bf(float f) {
    unsigned int u = __float_as_uint(f);
    u += 0x7fffu + ((u >> 16) & 1u);  // round-to-nearest-even
    return (unsigned short)(u >> 16);
}
// bf16 pair packed in u32 (lo = even feature, hi = odd feature)
__device__ __forceinline__ float lo_f(unsigned u) { return __uint_as_float(u << 16); }
__device__ __forceinline__ float hi_f(unsigned u) { return __uint_as_float(u & 0xffff0000u); }

// ---------------- CSR build ----------------

__global__ void k_init(int* __restrict__ cnt, int* __restrict__ bcur, int n, int nbkt) {
    int i = blockIdx.x * blockDim.x + threadIdx.x;
    if (i < n) cnt[i] = 0;
    if (i < nbkt) bcur[i] = 0;
}

__global__ void k_count(const int* __restrict__ dst, int* __restrict__ cnt, int E) {
    int e = blockIdx.x * blockDim.x + threadIdx.x;
    if (e < E) atomicAdd(&cnt[dst[e]], 1);
}

__global__ void k_dinv(const int* __restrict__ cnt, float* __restrict__ dinv, int n) {
    int i = blockIdx.x * blockDim.x + threadIdx.x;
    if (i < n) dinv[i] = rsqrtf((float)cnt[i] + 1.0f);  // +1 self-loop; deg >= 1 always
}

// inclusive scan within 256-blocks; rp[i+1] = local inclusive, bsum[b] = block total
__global__ void k_scan1(const int* __restrict__ cnt, int* __restrict__ rp,
                        int* __restrict__ bsum, int n) {
    __shared__ int s[SB];
    int t = threadIdx.x;
    int i = blockIdx.x * SB + t;
    int v = (i < n) ? cnt[i] : 0;
    s[t] = v;
    __syncthreads();
    for (int off = 1; off < SB; off <<= 1) {
        int u = (t >= off) ? s[t - off] : 0;
        __syncthreads();
        s[t] += u;
        __syncthreads();
    }
    if (i < n) rp[i + 1] = s[t];
    if (t == SB - 1) bsum[blockIdx.x] = s[t];
}

__global__ void k_scan2(const int* __restrict__ bsum, int* __restrict__ boff, int nb) {
    __shared__ int s[1024];
    int t = threadIdx.x;
    int v = (t < nb) ? bsum[t] : 0;
    s[t] = v;
    __syncthreads();
    for (int off = 1; off < 1024; off <<= 1) {
        int u = (t >= off) ? s[t - off] : 0;
        __syncthreads();
        s[t] += u;
        __syncthreads();
    }
    if (t < nb) boff[t] = s[t] - v;  // exclusive
}

__global__ void k_scan3(int* __restrict__ rp, const int* __restrict__ boff, int n) {
    int i = blockIdx.x * blockDim.x + threadIdx.x;
    if (i < n) {
        rp[i + 1] += boff[i / SB];
        if (i == 0) rp[0] = 0;
    }
}

// pass A: bucket-append packed (dstLocal<<26 | src). Writes land in 1563 hot
// contiguous regions -> L2 write-combining (vs random 4B = 64B line each).
__global__ void k_scatter(const int* __restrict__ src, const int* __restrict__ dst,
                          const int* __restrict__ rp, int* __restrict__ bcur,
                          unsigned* __restrict__ pairs, int E) {
    int e = blockIdx.x * blockDim.x + threadIdx.x;
    if (e >= E) return;
    int d = dst[e];
    int b = d >> BSH;
    int pos = atomicAdd(&bcur[b], 1);
    int base = rp[b << BSH];  // bucket base = rp at first node of bucket
    pairs[base + pos] = ((unsigned)(d & (BNODES - 1)) << 26) | (unsigned)src[e];
}

// pass B: one block per bucket; LDS per-node cursors; col writes stay inside
// the bucket's contiguous ~4KB range.
__global__ __launch_bounds__(256) void k_build(const unsigned* __restrict__ pairs,
                                               const int* __restrict__ rp,
                                               int* __restrict__ col, int N) {
    __shared__ int lcur[BNODES];
    int b = blockIdx.x;
    int n0 = b << BSH;
    int n1 = min(n0 + BNODES, N);
    int t = threadIdx.x;
    if (t < BNODES) lcur[t] = (n0 + t < N) ? rp[n0 + t] : 0;
    __syncthreads();
    int e0 = rp[n0], e1 = rp[n1];
    for (int e = e0 + t; e < e1; e += 256) {
        unsigned v = pairs[e];
        int dl = (int)(v >> 26);
        int s = (int)(v & 0x03FFFFFFu);
        int p = atomicAdd(&lcur[dl], 1);
        col[p] = s;
    }
}

// ---------------- x -> bf16, pre-scaled by dinv[row] ----------------
__global__ __launch_bounds__(256) void k_cvt(const float* __restrict__ x,
                                             const float* __restrict__ dinv,
                                             unsigned short* __restrict__ y, int nchunk) {
    int g = blockIdx.x * blockDim.x + threadIdx.x;
    if (g >= nchunk) return;
    int row = g >> 5;  // 32 chunks of 4 per 128-wide row
    float s = dinv[row];
    float4 v = reinterpret_cast<const float4*>(x)[g];
    ushort4 o;
    o.x = f2bf(v.x * s);
    o.y = f2bf(v.y * s);
    o.z = f2bf(v.z * s);
    o.w = f2bf(v.w * s);
    reinterpret_cast<ushort4*>(y)[g] = o;
}

// ---------------- normalized aggregation (gather, bf16 rows) ----------------
// out[n][f] = dinv[n] * ( y[n][f] + sum_{e in CSR(n)} y[col[e]][f] )
// One wave64 per node (uniform trip count, no intra-wave divergence); lane owns
// feature pair [2c,2c+2) as one u32; edge loop unrolled x4 for MLP.
__global__ __launch_bounds__(256) void k_agg(const unsigned short* __restrict__ y,
                                             float* __restrict__ out,
                                             const int* __restrict__ col,
                                             const int* __restrict__ rp,
                                             const float* __restrict__ dinv, int n) {
    int node = blockIdx.x * 4 + (threadIdx.x >> 6);
    if (node >= n) return;
    int c = threadIdx.x & 63;  // feature pair index
    const unsigned* yv = reinterpret_cast<const unsigned*>(y);

    unsigned v = yv[(size_t)node * 64 + c];  // self loop
    float a0 = lo_f(v), a1 = hi_f(v);

    int e0 = rp[node], e1 = rp[node + 1];
    int e = e0;
    for (; e + 4 <= e1; e += 4) {
        int s0 = col[e], s1 = col[e + 1], s2 = col[e + 2], s3 = col[e + 3];
        unsigned u0 = yv[(size_t)s0 * 64 + c];
        unsigned u1 = yv[(size_t)s1 * 64 + c];
        unsigned u2 = yv[(size_t)s2 * 64 + c];
        unsigned u3 = yv[(size_t)s3 * 64 + c];
        a0 += (lo_f(u0) + lo_f(u1)) + (lo_f(u2) + lo_f(u3));
        a1 += (hi_f(u0) + hi_f(u1)) + (hi_f(u2) + hi_f(u3));
    }
    for (; e < e1; ++e) {
        unsigned u = yv[(size_t)col[e] * 64 + c];
        a0 += lo_f(u);
        a1 += hi_f(u);
    }
    float dn = dinv[node];
    float2 o = make_float2(a0 * dn, a1 * dn);
    reinterpret_cast<float2*>(out)[(size_t)node * 64 + c] = o;
}

// ---------------- GEMM + bias + relu (f32, register tiled) ----------------
// STORE_BF16=1: y_bf16[r][c] = bf16(dinv[r] * relu(...)), f32 out not written.
// STORE_BF16=0: out_f32[r][c] = relu(...).
// In-place safe (A == out_f32): each block reads only its own 128 rows, and all
// A reads complete (K loop + syncthreads) before any store.
template <int STORE_BF16>
__global__ __launch_bounds__(256) void k_gemm(const float* __restrict__ A,
                                              const float* __restrict__ W,
                                              const float* __restrict__ bias,
                                              float* __restrict__ out_f32,
                                              unsigned short* __restrict__ out_bf16,
                                              const float* __restrict__ dinv, int N) {
    __shared__ float As[8][132];  // [k][row], padded
    __shared__ float Ws[8][132];  // [k][col], padded
    int tid = threadIdx.x;
    int row0 = blockIdx.x * 128;
    int ty = tid >> 4;   // 0..15 -> rows ty*8..+8
    int tx = tid & 15;   // 0..15 -> cols {tx*4..+4, 64+tx*4..+4}

    float acc[8][8];
#pragma unroll
    for (int i = 0; i < 8; ++i)
#pragma unroll
        for (int j = 0; j < 8; ++j) acc[i][j] = 0.0f;

    int ar = tid >> 1;            // 0..127
    int ac4 = (tid & 1) * 4;      // 0 or 4
    int wk = tid >> 5;            // 0..7
    int wc4 = (tid & 31) * 4;     // 0..124

    for (int kk = 0; kk < 128; kk += 8) {
        float4 av = make_float4(0.f, 0.f, 0.f, 0.f);
        if (row0 + ar < N)
            av = *reinterpret_cast<const float4*>(&A[(size_t)(row0 + ar) * 128 + kk + ac4]);
        As[ac4 + 0][ar] = av.x;
        As[ac4 + 1][ar] = av.y;
        As[ac4 + 2][ar] = av.z;
        As[ac4 + 3][ar] = av.w;
        float4 wv = *reinterpret_cast<const float4*>(&W[(size_t)(kk + wk) * 128 + wc4]);
        *reinterpret_cast<float4*>(&Ws[wk][wc4]) = wv;
        __syncthreads();

#pragma unroll
        for (int k = 0; k < 8; ++k) {
            float a[8], w[8];
#pragma unroll
            for (int i = 0; i < 8; ++i) a[i] = As[k][ty * 8 + i];
#pragma unroll
            for (int j = 0; j < 4; ++j) {
                w[j] = Ws[k][tx * 4 + j];
                w[4 + j] = Ws[k][64 + tx * 4 + j];
            }
#pragma unroll
            for (int i = 0; i < 8; ++i)
#pragma unroll
                for (int j = 0; j < 8; ++j) acc[i][j] = fmaf(a[i], w[j], acc[i][j]);
        }
        __syncthreads();
    }

#pragma unroll
    for (int i = 0; i < 8; ++i) {
        int r = row0 + ty * 8 + i;
        if (r < N) {
            if (STORE_BF16) {
                float s = dinv[r];
                ushort4 p0, p1;
                p0.x = f2bf(fmaxf(acc[i][0] + bias[tx * 4 + 0], 0.f) * s);
                p0.y = f2bf(fmaxf(acc[i][1] + bias[tx * 4 + 1], 0.f) * s);
                p0.z = f2bf(fmaxf(acc[i][2] + bias[tx * 4 + 2], 0.f) * s);
                p0.w = f2bf(fmaxf(acc[i][3] + bias[tx * 4 + 3], 0.f) * s);
                p1.x = f2bf(fmaxf(acc[i][4] + bias[64 + tx * 4 + 0], 0.f) * s);
                p1.y = f2bf(fmaxf(acc[i][5] + bias[64 + tx * 4 + 1], 0.f) * s);
                p1.z = f2bf(fmaxf(acc[i][6] + bias[64 + tx * 4 + 2], 0.f) * s);
                p1.w = f2bf(fmaxf(acc[i][7] + bias[64 + tx * 4 + 3], 0.f) * s);
                *reinterpret_cast<ushort4*>(&out_bf16[(size_t)r * 128 + tx * 4]) = p0;
                *reinterpret_cast<ushort4*>(&out_bf16[(size_t)r * 128 + 64 + tx * 4]) = p1;
            } else {
#pragma unroll
                for (int j = 0; j < 4; ++j) {
                    int c0 = tx * 4 + j;
                    int c1 = 64 + tx * 4 + j;
                    out_f32[(size_t)r * 128 + c0] = fmaxf(acc[i][j] + bias[c0], 0.0f);
                    out_f32[(size_t)r * 128 + c1] = fmaxf(acc[i][4 + j] + bias[c1], 0.0f);
                }
            }
        }
    }
}

// ---------------- launch ----------------

extern "C" void kernel_launch(void* const* d_in, const int* in_sizes, int n_in,
                              void* d_out, int out_size, void* d_ws, size_t ws_size,
                              hipStream_t stream) {
    const float* x  = (const float*)d_in[0];
    const int*   ei = (const int*)d_in[1];
    const float* W1 = (const float*)d_in[2];
    const float* b1 = (const float*)d_in[3];
    const float* W2 = (const float*)d_in[4];
    const float* b2 = (const float*)d_in[5];
    float* out = (float*)d_out;

    const int N = in_sizes[0] / D;
    const int E = in_sizes[1] / 2;
    const int* src = ei;
    const int* dst = ei + E;
    const int NBKT = (N + BNODES - 1) >> BSH;  // 1563 for N=100000

    char* w = (char*)d_ws;
    auto alloc = [&](size_t bytes) -> void* {
        void* p = (void*)w;
        w += (bytes + 255) & ~(size_t)255;
        return p;
    };
    float* dinv     = (float*)alloc((size_t)N * 4);
    int* cnt        = (int*)alloc((size_t)N * 4);
    int* rp         = (int*)alloc((size_t)(N + 1) * 4);
    int* bcur       = (int*)alloc((size_t)NBKT * 4);
    int* bsum       = (int*)alloc(4096);
    int* boff       = (int*)alloc(4096);
    unsigned* pairs = (unsigned*)alloc((size_t)E * 4);
    int* col        = (int*)alloc((size_t)E * 4);
    unsigned short* y = (unsigned short*)alloc((size_t)N * D * 2);

    const int nb = (N + SB - 1) / SB;  // 391 for N=100000, fits k_scan2's 1024

    k_init<<<(N + 255) / 256, 256, 0, stream>>>(cnt, bcur, N, NBKT);
    k_count<<<(E + 255) / 256, 256, 0, stream>>>(dst, cnt, E);
    k_dinv<<<(N + 255) / 256, 256, 0, stream>>>(cnt, dinv, N);
    k_scan1<<<nb, SB, 0, stream>>>(cnt, rp, bsum, N);
    k_scan2<<<1, 1024, 0, stream>>>(bsum, boff, nb);
    k_scan3<<<(N + 255) / 256, 256, 0, stream>>>(rp, boff, N);
    k_scatter<<<(E + 255) / 256, 256, 0, stream>>>(src, dst, rp, bcur, pairs, E);
    k_build<<<NBKT, 256, 0, stream>>>(pairs, rp, col, N);

    const int nchunk = N * (D / 4);
    const int aggblocks = (N + 3) / 4;

    // layer 1: y = bf16(dinv*x); a1 = agg(y) -> out; y = bf16(dinv*relu(a1@W1+b1))
    k_cvt<<<(nchunk + 255) / 256, 256, 0, stream>>>(x, dinv, y, nchunk);
    k_agg<<<aggblocks, 256, 0, stream>>>(y, out, col, rp, dinv, N);
    k_gemm<1><<<(N + 127) / 128, 256, 0, stream>>>(out, W1, b1, nullptr, y, dinv, N);
    // layer 2: a2 = agg(y) -> out; out = relu(a2@W2+b2) (in-place GEMM)
    k_agg<<<aggblocks, 256, 0, stream>>>(y, out, col, rp, dinv, N);
    k_gemm<0><<<(N + 127) / 128, 256, 0, stream>>>(out, W2, b2, out, nullptr, dinv, N);
}

// Round 4
// 426.520 us; speedup vs baseline: 1.3826x; 1.3826x over previous
//
#include <hip/hip_runtime.h>

#define D 128
#define SB 256
#define BSH 6                    // bucket = dst >> BSH  (64 nodes per bucket)
#define BNODES (1 << BSH)
#define NCHUNK 64                // edge chunks for counting sort (= wave size)
#define MAXBKT 2048              // LDS cursor capacity: supports N <= 131072

__device__ __forceinline__ float bf2f(unsigned short u) {
    return __uint_as_float(((unsigned int)u) << 16);
}
__device__ __forceinline__ unsigned short f2bf(float f) {
    unsigned int u = __float_as_uint(f);
    u += 0x7fffu + ((u >> 16) & 1u);  // round-to-nearest-even
    return (unsigned short)(u >> 16);
}
// bf16 pair packed in u32 (lo = even feature, hi = odd feature)
__device__ __forceinline__ float lo_f(unsigned u) { return __uint_as_float(u << 16); }
__device__ __forceinline__ float hi_f(unsigned u) { return __uint_as_float(u & 0xffff0000u); }

// ---------------- CSR build (contention-free counting sort) ----------------

__global__ void k_init(int* __restrict__ cnt, int n) {
    int i = blockIdx.x * blockDim.x + threadIdx.x;
    if (i < n) cnt[i] = 0;
}

// chunk c: per-node degree atomics (spread over N addrs, low contention) +
// LDS bucket histogram -> cnts[c][b]. grid = NCHUNK blocks.
__global__ __launch_bounds__(256) void k_histcount(const int* __restrict__ dst,
                                                   int* __restrict__ cnt,
                                                   int* __restrict__ cnts,
                                                   int E, int nbkt, int chunk) {
    __shared__ int hist[MAXBKT];
    int c = blockIdx.x;
    int t = threadIdx.x;
    for (int i = t; i < nbkt; i += 256) hist[i] = 0;
    __syncthreads();
    int e0 = c * chunk, e1 = min(e0 + chunk, E);
    for (int e = e0 + t; e < e1; e += 256) {
        int d = dst[e];
        atomicAdd(&cnt[d], 1);
        atomicAdd(&hist[d >> BSH], 1);
    }
    __syncthreads();
    for (int i = t; i < nbkt; i += 256) cnts[c * nbkt + i] = hist[i];
}

__global__ void k_dinv(const int* __restrict__ cnt, float* __restrict__ dinv, int n) {
    int i = blockIdx.x * blockDim.x + threadIdx.x;
    if (i < n) dinv[i] = rsqrtf((float)cnt[i] + 1.0f);  // +1 self-loop; deg >= 1 always
}

// inclusive scan within 256-blocks; rp[i+1] = local inclusive, bsum[b] = block total
__global__ void k_scan1(const int* __restrict__ cnt, int* __restrict__ rp,
                        int* __restrict__ bsum, int n) {
    __shared__ int s[SB];
    int t = threadIdx.x;
    int i = blockIdx.x * SB + t;
    int v = (i < n) ? cnt[i] : 0;
    s[t] = v;
    __syncthreads();
    for (int off = 1; off < SB; off <<= 1) {
        int u = (t >= off) ? s[t - off] : 0;
        __syncthreads();
        s[t] += u;
        __syncthreads();
    }
    if (i < n) rp[i + 1] = s[t];
    if (t == SB - 1) bsum[blockIdx.x] = s[t];
}

__global__ void k_scan2(const int* __restrict__ bsum, int* __restrict__ boff, int nb) {
    __shared__ int s[1024];
    int t = threadIdx.x;
    int v = (t < nb) ? bsum[t] : 0;
    s[t] = v;
    __syncthreads();
    for (int off = 1; off < 1024; off <<= 1) {
        int u = (t >= off) ? s[t - off] : 0;
        __syncthreads();
        s[t] += u;
        __syncthreads();
    }
    if (t < nb) boff[t] = s[t] - v;  // exclusive
}

__global__ void k_scan3(int* __restrict__ rp, const int* __restrict__ boff, int n) {
    int i = blockIdx.x * blockDim.x + threadIdx.x;
    if (i < n) {
        rp[i + 1] += boff[i / SB];
        if (i == 0) rp[0] = 0;
    }
}

// one wave per bucket, lane l = chunk l: cnts[c][b] <- rp[b<<6] + excl-scan_c(cnts)
__global__ void k_chunkscan(int* __restrict__ cnts, const int* __restrict__ rp, int nbkt) {
    int w = (blockIdx.x * blockDim.x + threadIdx.x) >> 6;  // bucket (wave-uniform)
    if (w >= nbkt) return;
    int l = threadIdx.x & 63;                              // chunk
    int v = cnts[l * nbkt + w];
    int x = v;
#pragma unroll
    for (int off = 1; off < 64; off <<= 1) {
        int u = __shfl_up(x, off);
        if (l >= off) x += u;
    }
    cnts[l * nbkt + w] = rp[w << BSH] + (x - v);  // exclusive + bucket base
}

// chunk c: place packed (dstLocal<<26 | src) at precomputed per-chunk bucket
// offsets; cursors advance via LDS atomics only.
__global__ __launch_bounds__(256) void k_place(const int* __restrict__ src,
                                               const int* __restrict__ dst,
                                               const int* __restrict__ cnts,
                                               unsigned* __restrict__ pairs,
                                               int E, int nbkt, int chunk) {
    __shared__ int cur[MAXBKT];
    int c = blockIdx.x;
    int t = threadIdx.x;
    for (int i = t; i < nbkt; i += 256) cur[i] = cnts[c * nbkt + i];
    __syncthreads();
    int e0 = c * chunk, e1 = min(e0 + chunk, E);
    for (int e = e0 + t; e < e1; e += 256) {
        int d = dst[e];
        int p = atomicAdd(&cur[d >> BSH], 1);
        pairs[p] = ((unsigned)(d & (BNODES - 1)) << 26) | (unsigned)src[e];
    }
}

// one block per bucket; LDS per-node cursors; col writes stay inside the
// bucket's contiguous ~4KB range.
__global__ __launch_bounds__(256) void k_build(const unsigned* __restrict__ pairs,
                                               const int* __restrict__ rp,
                                               int* __restrict__ col, int N) {
    __shared__ int lcur[BNODES];
    int b = blockIdx.x;
    int n0 = b << BSH;
    int n1 = min(n0 + BNODES, N);
    int t = threadIdx.x;
    if (t < BNODES) lcur[t] = (n0 + t < N) ? rp[n0 + t] : 0;
    __syncthreads();
    int e0 = rp[n0], e1 = rp[n1];
    for (int e = e0 + t; e < e1; e += 256) {
        unsigned v = pairs[e];
        int dl = (int)(v >> 26);
        int s = (int)(v & 0x03FFFFFFu);
        int p = atomicAdd(&lcur[dl], 1);
        col[p] = s;
    }
}

// ---------------- x -> bf16, pre-scaled by dinv[row] ----------------
__global__ __launch_bounds__(256) void k_cvt(const float* __restrict__ x,
                                             const float* __restrict__ dinv,
                                             unsigned short* __restrict__ y, int nchunk) {
    int g = blockIdx.x * blockDim.x + threadIdx.x;
    if (g >= nchunk) return;
    int row = g >> 5;  // 32 chunks of 4 per 128-wide row
    float s = dinv[row];
    float4 v = reinterpret_cast<const float4*>(x)[g];
    ushort4 o;
    o.x = f2bf(v.x * s);
    o.y = f2bf(v.y * s);
    o.z = f2bf(v.z * s);
    o.w = f2bf(v.w * s);
    reinterpret_cast<ushort4*>(y)[g] = o;
}

// ---------------- normalized aggregation (gather, bf16 rows) ----------------
// out[n][f] = dinv[n] * ( y[n][f] + sum_{e in CSR(n)} y[col[e]][f] )
// One wave64 per node; lane owns feature pair as one u32; edge loop unrolled x4.
__global__ __launch_bounds__(256) void k_agg(const unsigned short* __restrict__ y,
                                             float* __restrict__ out,
                                             const int* __restrict__ col,
                                             const int* __restrict__ rp,
                                             const float* __restrict__ dinv, int n) {
    int node = blockIdx.x * 4 + (threadIdx.x >> 6);
    if (node >= n) return;
    int c = threadIdx.x & 63;  // feature pair index
    const unsigned* yv = reinterpret_cast<const unsigned*>(y);

    unsigned v = yv[(size_t)node * 64 + c];  // self loop
    float a0 = lo_f(v), a1 = hi_f(v);

    int e0 = rp[node], e1 = rp[node + 1];
    int e = e0;
    for (; e + 4 <= e1; e += 4) {
        int s0 = col[e], s1 = col[e + 1], s2 = col[e + 2], s3 = col[e + 3];
        unsigned u0 = yv[(size_t)s0 * 64 + c];
        unsigned u1 = yv[(size_t)s1 * 64 + c];
        unsigned u2 = yv[(size_t)s2 * 64 + c];
        unsigned u3 = yv[(size_t)s3 * 64 + c];
        a0 += (lo_f(u0) + lo_f(u1)) + (lo_f(u2) + lo_f(u3));
        a1 += (hi_f(u0) + hi_f(u1)) + (hi_f(u2) + hi_f(u3));
    }
    for (; e < e1; ++e) {
        unsigned u = yv[(size_t)col[e] * 64 + c];
        a0 += lo_f(u);
        a1 += hi_f(u);
    }
    float dn = dinv[node];
    float2 o = make_float2(a0 * dn, a1 * dn);
    reinterpret_cast<float2*>(out)[(size_t)node * 64 + c] = o;
}

// ---------------- GEMM + bias + relu (f32, register tiled) ----------------
// STORE_BF16=1: y_bf16[r][c] = bf16(dinv[r] * relu(...)), f32 out not written.
// STORE_BF16=0: out_f32[r][c] = relu(...).
// In-place safe (A == out_f32): each block reads only its own 128 rows, and all
// A reads complete (K loop + syncthreads) before any store.
template <int STORE_BF16>
__global__ __launch_bounds__(256) void k_gemm(const float* __restrict__ A,
                                              const float* __restrict__ W,
                                              const float* __restrict__ bias,
                                              float* __restrict__ out_f32,
                                              unsigned short* __restrict__ out_bf16,
                                              const float* __restrict__ dinv, int N) {
    __shared__ float As[8][132];  // [k][row], padded
    __shared__ float Ws[8][132];  // [k][col], padded
    int tid = threadIdx.x;
    int row0 = blockIdx.x * 128;
    int ty = tid >> 4;   // 0..15 -> rows ty*8..+8
    int tx = tid & 15;   // 0..15 -> cols {tx*4..+4, 64+tx*4..+4}

    float acc[8][8];
#pragma unroll
    for (int i = 0; i < 8; ++i)
#pragma unroll
        for (int j = 0; j < 8; ++j) acc[i][j] = 0.0f;

    int ar = tid >> 1;            // 0..127
    int ac4 = (tid & 1) * 4;      // 0 or 4
    int wk = tid >> 5;            // 0..7
    int wc4 = (tid & 31) * 4;     // 0..124

    for (int kk = 0; kk < 128; kk += 8) {
        float4 av = make_float4(0.f, 0.f, 0.f, 0.f);
        if (row0 + ar < N)
            av = *reinterpret_cast<const float4*>(&A[(size_t)(row0 + ar) * 128 + kk + ac4]);
        As[ac4 + 0][ar] = av.x;
        As[ac4 + 1][ar] = av.y;
        As[ac4 + 2][ar] = av.z;
        As[ac4 + 3][ar] = av.w;
        float4 wv = *reinterpret_cast<const float4*>(&W[(size_t)(kk + wk) * 128 + wc4]);
        *reinterpret_cast<float4*>(&Ws[wk][wc4]) = wv;
        __syncthreads();

#pragma unroll
        for (int k = 0; k < 8; ++k) {
            float a[8], w[8];
#pragma unroll
            for (int i = 0; i < 8; ++i) a[i] = As[k][ty * 8 + i];
#pragma unroll
            for (int j = 0; j < 4; ++j) {
                w[j] = Ws[k][tx * 4 + j];
                w[4 + j] = Ws[k][64 + tx * 4 + j];
            }
#pragma unroll
            for (int i = 0; i < 8; ++i)
#pragma unroll
                for (int j = 0; j < 8; ++j) acc[i][j] = fmaf(a[i], w[j], acc[i][j]);
        }
        __syncthreads();
    }

#pragma unroll
    for (int i = 0; i < 8; ++i) {
        int r = row0 + ty * 8 + i;
        if (r < N) {
            if (STORE_BF16) {
                float s = dinv[r];
                ushort4 p0, p1;
                p0.x = f2bf(fmaxf(acc[i][0] + bias[tx * 4 + 0], 0.f) * s);
                p0.y = f2bf(fmaxf(acc[i][1] + bias[tx * 4 + 1], 0.f) * s);
                p0.z = f2bf(fmaxf(acc[i][2] + bias[tx * 4 + 2], 0.f) * s);
                p0.w = f2bf(fmaxf(acc[i][3] + bias[tx * 4 + 3], 0.f) * s);
                p1.x = f2bf(fmaxf(acc[i][4] + bias[64 + tx * 4 + 0], 0.f) * s);
                p1.y = f2bf(fmaxf(acc[i][5] + bias[64 + tx * 4 + 1], 0.f) * s);
                p1.z = f2bf(fmaxf(acc[i][6] + bias[64 + tx * 4 + 2], 0.f) * s);
                p1.w = f2bf(fmaxf(acc[i][7] + bias[64 + tx * 4 + 3], 0.f) * s);
                *reinterpret_cast<ushort4*>(&out_bf16[(size_t)r * 128 + tx * 4]) = p0;
                *reinterpret_cast<ushort4*>(&out_bf16[(size_t)r * 128 + 64 + tx * 4]) = p1;
            } else {
#pragma unroll
                for (int j = 0; j < 4; ++j) {
                    int c0 = tx * 4 + j;
                    int c1 = 64 + tx * 4 + j;
                    out_f32[(size_t)r * 128 + c0] = fmaxf(acc[i][j] + bias[c0], 0.0f);
                    out_f32[(size_t)r * 128 + c1] = fmaxf(acc[i][4 + j] + bias[c1], 0.0f);
                }
            }
        }
    }
}

// ---------------- launch ----------------

extern "C" void kernel_launch(void* const* d_in, const int* in_sizes, int n_in,
                              void* d_out, int out_size, void* d_ws, size_t ws_size,
                              hipStream_t stream) {
    const float* x  = (const float*)d_in[0];
    const int*   ei = (const int*)d_in[1];
    const float* W1 = (const float*)d_in[2];
    const float* b1 = (const float*)d_in[3];
    const float* W2 = (const float*)d_in[4];
    const float* b2 = (const float*)d_in[5];
    float* out = (float*)d_out;

    const int N = in_sizes[0] / D;
    const int E = in_sizes[1] / 2;
    const int* src = ei;
    const int* dst = ei + E;
    const int NBKT = (N + BNODES - 1) >> BSH;        // 1563 for N=100000 (<= MAXBKT)
    const int CHUNK = (E + NCHUNK - 1) / NCHUNK;     // 25000 for E=1.6M

    char* w = (char*)d_ws;
    auto alloc = [&](size_t bytes) -> void* {
        void* p = (void*)w;
        w += (bytes + 255) & ~(size_t)255;
        return p;
    };
    float* dinv     = (float*)alloc((size_t)N * 4);
    int* cnt        = (int*)alloc((size_t)N * 4);
    int* rp         = (int*)alloc((size_t)(N + 1) * 4);
    int* cnts       = (int*)alloc((size_t)NCHUNK * NBKT * 4);
    int* bsum       = (int*)alloc(4096);
    int* boff       = (int*)alloc(4096);
    unsigned* pairs = (unsigned*)alloc((size_t)E * 4);
    int* col        = (int*)alloc((size_t)E * 4);
    unsigned short* y = (unsigned short*)alloc((size_t)N * D * 2);

    const int nb = (N + SB - 1) / SB;  // 391 for N=100000, fits k_scan2's 1024

    k_init<<<(N + 255) / 256, 256, 0, stream>>>(cnt, N);
    k_histcount<<<NCHUNK, 256, 0, stream>>>(dst, cnt, cnts, E, NBKT, CHUNK);
    k_dinv<<<(N + 255) / 256, 256, 0, stream>>>(cnt, dinv, N);
    k_scan1<<<nb, SB, 0, stream>>>(cnt, rp, bsum, N);
    k_scan2<<<1, 1024, 0, stream>>>(bsum, boff, nb);
    k_scan3<<<(N + 255) / 256, 256, 0, stream>>>(rp, boff, N);
    k_chunkscan<<<(NBKT * 64 + 255) / 256, 256, 0, stream>>>(cnts, rp, NBKT);
    k_place<<<NCHUNK, 256, 0, stream>>>(src, dst, cnts, pairs, E, NBKT, CHUNK);
    k_build<<<NBKT, 256, 0, stream>>>(pairs, rp, col, N);

    const int nchunk = N * (D / 4);
    const int aggblocks = (N + 3) / 4;

    // layer 1: y = bf16(dinv*x); a1 = agg(y) -> out; y = bf16(dinv*relu(a1@W1+b1))
    k_cvt<<<(nchunk + 255) / 256, 256, 0, stream>>>(x, dinv, y, nchunk);
    k_agg<<<aggblocks, 256, 0, stream>>>(y, out, col, rp, dinv, N);
    k_gemm<1><<<(N + 127) / 128, 256, 0, stream>>>(out, W1, b1, nullptr, y, dinv, N);
    // layer 2: a2 = agg(y) -> out; out = relu(a2@W2+b2) (in-place GEMM)
    k_agg<<<aggblocks, 256, 0, stream>>>(y, out, col, rp, dinv, N);
    k_gemm<0><<<(N + 127) / 128, 256, 0, stream>>>(out, W2, b2, out, nullptr, dinv, N);
}

// Round 5
// 306.045 us; speedup vs baseline: 1.9269x; 1.3937x over previous
//
#include <hip/hip_runtime.h>

#define D 128
#define BSH 8                    // bucket = dst >> BSH (256 nodes per bucket)
#define BNODES (1 << BSH)
#define NCHUNK 512               // edge chunks; grid of place/hist kernels
#define MAXB 512                 // LDS bucket-array capacity (NBKT <= 512, N <= 131072)

__device__ __forceinline__ unsigned short f2bf(float f) {
    unsigned int u = __float_as_uint(f);
    u += 0x7fffu + ((u >> 16) & 1u);  // round-to-nearest-even
    return (unsigned short)(u >> 16);
}
// bf16 pair packed in u32 (lo = even feature, hi = odd feature)
__device__ __forceinline__ float lo_f(unsigned u) { return __uint_as_float(u << 16); }
__device__ __forceinline__ float hi_f(unsigned u) { return __uint_as_float(u & 0xffff0000u); }

// ---------------- CSR build: contention-free counting sort ----------------
// pairs layout: (dstLocal<<24) | src   (needs N < 2^24, BNODES <= 256)

// chunk c: LDS histogram of dst buckets -> cnts[b][c] (bucket-major)
__global__ __launch_bounds__(256) void k_hist(const int* __restrict__ dst,
                                              int* __restrict__ cnts,
                                              int E, int nbkt, int chunk) {
    __shared__ int hist[MAXB];
    int c = blockIdx.x;
    int t = threadIdx.x;
    for (int i = t; i < nbkt; i += 256) hist[i] = 0;
    __syncthreads();
    int e0 = c * chunk, e1 = min(e0 + chunk, E);
    for (int e = e0 + t; e < e1; e += 256) atomicAdd(&hist[dst[e] >> BSH], 1);
    __syncthreads();
    for (int i = t; i < nbkt; i += 256) cnts[(size_t)i * NCHUNK + c] = hist[i];
}

// one wave per bucket: exclusive scan over the NCHUNK chunk-counts (in place),
// bucket total -> btot[b]. cnts reads/writes are lane-coalesced.
__global__ __launch_bounds__(256) void k_chunksum(int* __restrict__ cnts,
                                                  int* __restrict__ btot, int nbkt) {
    int b = blockIdx.x * 4 + (threadIdx.x >> 6);
    if (b >= nbkt) return;
    int l = threadIdx.x & 63;
    int carry = 0;
    for (int g = 0; g < NCHUNK; g += 64) {
        int v = cnts[(size_t)b * NCHUNK + g + l];
        int x = v;
#pragma unroll
        for (int off = 1; off < 64; off <<= 1) {
            int u = __shfl_up(x, off);
            if (l >= off) x += u;
        }
        cnts[(size_t)b * NCHUNK + g + l] = carry + x - v;  // exclusive
        carry += __shfl(x, 63);
    }
    if (l == 0) btot[b] = carry;
}

// one block: exclusive scan of bucket totals -> bbase[0..nbkt] (bbase[nbkt] = E)
__global__ __launch_bounds__(MAXB) void k_bktscan(const int* __restrict__ btot,
                                                  int* __restrict__ bbase, int nbkt) {
    __shared__ int s[MAXB];
    int t = threadIdx.x;
    int v = (t < nbkt) ? btot[t] : 0;
    s[t] = v;
    __syncthreads();
    for (int off = 1; off < MAXB; off <<= 1) {
        int u = (t >= off) ? s[t - off] : 0;
        __syncthreads();
        s[t] += u;
        __syncthreads();
    }
    if (t < nbkt) bbase[t + 1] = s[t];
    if (t == 0) bbase[0] = 0;
}

// chunk c: place packed pairs at precomputed per-(chunk,bucket) offsets;
// cursors advance via LDS atomics only. ~8 edges/bucket/chunk -> writes have
// 32B/line locality.
__global__ __launch_bounds__(256) void k_place(const int* __restrict__ src,
                                               const int* __restrict__ dst,
                                               const int* __restrict__ cnts,
                                               const int* __restrict__ bbase,
                                               unsigned* __restrict__ pairs,
                                               int E, int nbkt, int chunk) {
    __shared__ int cur[MAXB];
    int c = blockIdx.x;
    int t = threadIdx.x;
    for (int i = t; i < nbkt; i += 256)
        cur[i] = bbase[i] + cnts[(size_t)i * NCHUNK + c];
    __syncthreads();
    int e0 = c * chunk, e1 = min(e0 + chunk, E);
    for (int e = e0 + t; e < e1; e += 256) {
        int d = dst[e];
        int p = atomicAdd(&cur[d >> BSH], 1);
        pairs[p] = ((unsigned)(d & (BNODES - 1)) << 24) | (unsigned)src[e];
    }
}

// one block per bucket: derive per-node degree (LDS count over pairs), LDS scan
// -> rp + dinv + local cursors, then scatter col within the bucket's region.
__global__ __launch_bounds__(BNODES) void k_build(const unsigned* __restrict__ pairs,
                                                  const int* __restrict__ bbase,
                                                  int* __restrict__ rp,
                                                  float* __restrict__ dinv,
                                                  int* __restrict__ col, int N) {
    __shared__ int cntL[BNODES];
    __shared__ int lcur[BNODES];
    int b = blockIdx.x;
    int n0 = b << BSH;
    int t = threadIdx.x;
    int e0 = bbase[b], e1 = bbase[b + 1];

    cntL[t] = 0;
    __syncthreads();
    for (int e = e0 + t; e < e1; e += BNODES)
        atomicAdd(&cntL[pairs[e] >> 24], 1);
    __syncthreads();
    int deg = cntL[t];
    // inclusive scan of cntL (Hillis-Steele, in place)
    for (int off = 1; off < BNODES; off <<= 1) {
        int u = (t >= off) ? cntL[t - off] : 0;
        __syncthreads();
        cntL[t] += u;
        __syncthreads();
    }
    int rpv = e0 + cntL[t] - deg;  // exclusive + bucket base
    lcur[t] = rpv;
    int node = n0 + t;
    if (node < N) {
        rp[node] = rpv;
        dinv[node] = rsqrtf((float)deg + 1.0f);  // +1 self-loop
        if (node == N - 1) rp[N] = e1;
    }
    __syncthreads();
    for (int e = e0 + t; e < e1; e += BNODES) {
        unsigned v = pairs[e];
        int p = atomicAdd(&lcur[v >> 24], 1);
        col[p] = (int)(v & 0x00FFFFFFu);
    }
}

// ---------------- x -> bf16, pre-scaled by dinv[row] ----------------
__global__ __launch_bounds__(256) void k_cvt(const float* __restrict__ x,
                                             const float* __restrict__ dinv,
                                             unsigned short* __restrict__ y, int nchunk) {
    int g = blockIdx.x * blockDim.x + threadIdx.x;
    if (g >= nchunk) return;
    int row = g >> 5;  // 32 chunks of 4 per 128-wide row
    float s = dinv[row];
    float4 v = reinterpret_cast<const float4*>(x)[g];
    ushort4 o;
    o.x = f2bf(v.x * s);
    o.y = f2bf(v.y * s);
    o.z = f2bf(v.z * s);
    o.w = f2bf(v.w * s);
    reinterpret_cast<ushort4*>(y)[g] = o;
}

// ---------------- normalized aggregation (gather, bf16 rows) ----------------
// out[n][f] = dinv[n] * ( y[n][f] + sum_{e in CSR(n)} y[col[e]][f] )
// One wave64 per node; lane owns feature pair as one u32; edge loop unrolled x4.
__global__ __launch_bounds__(256) void k_agg(const unsigned short* __restrict__ y,
                                             float* __restrict__ out,
                                             const int* __restrict__ col,
                                             const int* __restrict__ rp,
                                             const float* __restrict__ dinv, int n) {
    int node = blockIdx.x * 4 + (threadIdx.x >> 6);
    if (node >= n) return;
    int c = threadIdx.x & 63;  // feature pair index
    const unsigned* yv = reinterpret_cast<const unsigned*>(y);

    unsigned v = yv[(size_t)node * 64 + c];  // self loop
    float a0 = lo_f(v), a1 = hi_f(v);

    int e0 = rp[node], e1 = rp[node + 1];
    int e = e0;
    for (; e + 4 <= e1; e += 4) {
        int s0 = col[e], s1 = col[e + 1], s2 = col[e + 2], s3 = col[e + 3];
        unsigned u0 = yv[(size_t)s0 * 64 + c];
        unsigned u1 = yv[(size_t)s1 * 64 + c];
        unsigned u2 = yv[(size_t)s2 * 64 + c];
        unsigned u3 = yv[(size_t)s3 * 64 + c];
        a0 += (lo_f(u0) + lo_f(u1)) + (lo_f(u2) + lo_f(u3));
        a1 += (hi_f(u0) + hi_f(u1)) + (hi_f(u2) + hi_f(u3));
    }
    for (; e < e1; ++e) {
        unsigned u = yv[(size_t)col[e] * 64 + c];
        a0 += lo_f(u);
        a1 += hi_f(u);
    }
    float dn = dinv[node];
    float2 o = make_float2(a0 * dn, a1 * dn);
    reinterpret_cast<float2*>(out)[(size_t)node * 64 + c] = o;
}

// ---------------- GEMM + bias + relu (f32, register tiled) ----------------
// STORE_BF16=1: y_bf16[r][c] = bf16(dinv[r] * relu(...)), f32 out not written.
// STORE_BF16=0: out_f32[r][c] = relu(...).
// In-place safe (A == out_f32): each block reads only its own 128 rows, and all
// A reads complete (K loop + syncthreads) before any store.
template <int STORE_BF16>
__global__ __launch_bounds__(256) void k_gemm(const float* __restrict__ A,
                                              const float* __restrict__ W,
                                              const float* __restrict__ bias,
                                              float* __restrict__ out_f32,
                                              unsigned short* __restrict__ out_bf16,
                                              const float* __restrict__ dinv, int N) {
    __shared__ float As[8][132];  // [k][row], padded
    __shared__ float Ws[8][132];  // [k][col], padded
    int tid = threadIdx.x;
    int row0 = blockIdx.x * 128;
    int ty = tid >> 4;   // 0..15 -> rows ty*8..+8
    int tx = tid & 15;   // 0..15 -> cols {tx*4..+4, 64+tx*4..+4}

    float acc[8][8];
#pragma unroll
    for (int i = 0; i < 8; ++i)
#pragma unroll
        for (int j = 0; j < 8; ++j) acc[i][j] = 0.0f;

    int ar = tid >> 1;            // 0..127
    int ac4 = (tid & 1) * 4;      // 0 or 4
    int wk = tid >> 5;            // 0..7
    int wc4 = (tid & 31) * 4;     // 0..124

    for (int kk = 0; kk < 128; kk += 8) {
        float4 av = make_float4(0.f, 0.f, 0.f, 0.f);
        if (row0 + ar < N)
            av = *reinterpret_cast<const float4*>(&A[(size_t)(row0 + ar) * 128 + kk + ac4]);
        As[ac4 + 0][ar] = av.x;
        As[ac4 + 1][ar] = av.y;
        As[ac4 + 2][ar] = av.z;
        As[ac4 + 3][ar] = av.w;
        float4 wv = *reinterpret_cast<const float4*>(&W[(size_t)(kk + wk) * 128 + wc4]);
        *reinterpret_cast<float4*>(&Ws[wk][wc4]) = wv;
        __syncthreads();

#pragma unroll
        for (int k = 0; k < 8; ++k) {
            float a[8], w[8];
#pragma unroll
            for (int i = 0; i < 8; ++i) a[i] = As[k][ty * 8 + i];
#pragma unroll
            for (int j = 0; j < 4; ++j) {
                w[j] = Ws[k][tx * 4 + j];
                w[4 + j] = Ws[k][64 + tx * 4 + j];
            }
#pragma unroll
            for (int i = 0; i < 8; ++i)
#pragma unroll
                for (int j = 0; j < 8; ++j) acc[i][j] = fmaf(a[i], w[j], acc[i][j]);
        }
        __syncthreads();
    }

#pragma unroll
    for (int i = 0; i < 8; ++i) {
        int r = row0 + ty * 8 + i;
        if (r < N) {
            if (STORE_BF16) {
                float s = dinv[r];
                ushort4 p0, p1;
                p0.x = f2bf(fmaxf(acc[i][0] + bias[tx * 4 + 0], 0.f) * s);
                p0.y = f2bf(fmaxf(acc[i][1] + bias[tx * 4 + 1], 0.f) * s);
                p0.z = f2bf(fmaxf(acc[i][2] + bias[tx * 4 + 2], 0.f) * s);
                p0.w = f2bf(fmaxf(acc[i][3] + bias[tx * 4 + 3], 0.f) * s);
                p1.x = f2bf(fmaxf(acc[i][4] + bias[64 + tx * 4 + 0], 0.f) * s);
                p1.y = f2bf(fmaxf(acc[i][5] + bias[64 + tx * 4 + 1], 0.f) * s);
                p1.z = f2bf(fmaxf(acc[i][6] + bias[64 + tx * 4 + 2], 0.f) * s);
                p1.w = f2bf(fmaxf(acc[i][7] + bias[64 + tx * 4 + 3], 0.f) * s);
                *reinterpret_cast<ushort4*>(&out_bf16[(size_t)r * 128 + tx * 4]) = p0;
                *reinterpret_cast<ushort4*>(&out_bf16[(size_t)r * 128 + 64 + tx * 4]) = p1;
            } else {
#pragma unroll
                for (int j = 0; j < 4; ++j) {
                    int c0 = tx * 4 + j;
                    int c1 = 64 + tx * 4 + j;
                    out_f32[(size_t)r * 128 + c0] = fmaxf(acc[i][j] + bias[c0], 0.0f);
                    out_f32[(size_t)r * 128 + c1] = fmaxf(acc[i][4 + j] + bias[c1], 0.0f);
                }
            }
        }
    }
}

// ---------------- launch ----------------

extern "C" void kernel_launch(void* const* d_in, const int* in_sizes, int n_in,
                              void* d_out, int out_size, void* d_ws, size_t ws_size,
                              hipStream_t stream) {
    const float* x  = (const float*)d_in[0];
    const int*   ei = (const int*)d_in[1];
    const float* W1 = (const float*)d_in[2];
    const float* b1 = (const float*)d_in[3];
    const float* W2 = (const float*)d_in[4];
    const float* b2 = (const float*)d_in[5];
    float* out = (float*)d_out;

    const int N = in_sizes[0] / D;
    const int E = in_sizes[1] / 2;
    const int* src = ei;
    const int* dst = ei + E;
    const int NBKT = (N + BNODES - 1) >> BSH;     // 391 for N=100000 (<= MAXB)
    const int CHUNK = (E + NCHUNK - 1) / NCHUNK;  // 3125 for E=1.6M

    char* w = (char*)d_ws;
    auto alloc = [&](size_t bytes) -> void* {
        void* p = (void*)w;
        w += (bytes + 255) & ~(size_t)255;
        return p;
    };
    float* dinv     = (float*)alloc((size_t)N * 4);
    int* rp         = (int*)alloc((size_t)(N + 1) * 4);
    int* cnts       = (int*)alloc((size_t)NBKT * NCHUNK * 4);  // ~0.8 MB
    int* btot       = (int*)alloc((size_t)NBKT * 4);
    int* bbase      = (int*)alloc((size_t)(NBKT + 1) * 4);
    unsigned* pairs = (unsigned*)alloc((size_t)E * 4);
    int* col        = (int*)alloc((size_t)E * 4);
    unsigned short* y = (unsigned short*)alloc((size_t)N * D * 2);

    k_hist<<<NCHUNK, 256, 0, stream>>>(dst, cnts, E, NBKT, CHUNK);
    k_chunksum<<<(NBKT + 3) / 4, 256, 0, stream>>>(cnts, btot, NBKT);
    k_bktscan<<<1, MAXB, 0, stream>>>(btot, bbase, NBKT);
    k_place<<<NCHUNK, 256, 0, stream>>>(src, dst, cnts, bbase, pairs, E, NBKT, CHUNK);
    k_build<<<NBKT, BNODES, 0, stream>>>(pairs, bbase, rp, dinv, col, N);

    const int nchunk = N * (D / 4);
    const int aggblocks = (N + 3) / 4;

    // layer 1: y = bf16(dinv*x); a1 = agg(y) -> out; y = bf16(dinv*relu(a1@W1+b1))
    k_cvt<<<(nchunk + 255) / 256, 256, 0, stream>>>(x, dinv, y, nchunk);
    k_agg<<<aggblocks, 256, 0, stream>>>(y, out, col, rp, dinv, N);
    k_gemm<1><<<(N + 127) / 128, 256, 0, stream>>>(out, W1, b1, nullptr, y, dinv, N);
    // layer 2: a2 = agg(y) -> out; out = relu(a2@W2+b2) (in-place GEMM)
    k_agg<<<aggblocks, 256, 0, stream>>>(y, out, col, rp, dinv, N);
    k_gemm<0><<<(N + 127) / 128, 256, 0, stream>>>(out, W2, b2, out, nullptr, dinv, N);
}

// Round 6
// 239.254 us; speedup vs baseline: 2.4648x; 1.2792x over previous
//
#include <hip/hip_runtime.h>

#define D 128
#define BSH 8                    // bucket = dst >> BSH (256 nodes per bucket)
#define BNODES (1 << BSH)
#define NCHUNK 512               // edge chunks; grid of place/hist kernels
#define MAXB 512                 // LDS bucket-array capacity (NBKT <= 512, N <= 131072)

typedef __attribute__((ext_vector_type(8))) __bf16 bf16x8;
typedef __attribute__((ext_vector_type(4))) float f32x4;

__device__ __forceinline__ unsigned short f2bf(float f) {
    unsigned int u = __float_as_uint(f);
    u += 0x7fffu + ((u >> 16) & 1u);  // round-to-nearest-even
    return (unsigned short)(u >> 16);
}
// bf16 pair packed in u32 (lo = even feature, hi = odd feature)
__device__ __forceinline__ float lo_f(unsigned u) { return __uint_as_float(u << 16); }
__device__ __forceinline__ float hi_f(unsigned u) { return __uint_as_float(u & 0xffff0000u); }

// ---------------- CSR build: contention-free counting sort ----------------
// pairs layout: (dstLocal<<24) | src   (needs N < 2^24, BNODES <= 256)

__global__ __launch_bounds__(256) void k_hist(const int* __restrict__ dst,
                                              int* __restrict__ cnts,
                                              int E, int nbkt, int chunk) {
    __shared__ int hist[MAXB];
    int c = blockIdx.x;
    int t = threadIdx.x;
    for (int i = t; i < nbkt; i += 256) hist[i] = 0;
    __syncthreads();
    int e0 = c * chunk, e1 = min(e0 + chunk, E);
    for (int e = e0 + t; e < e1; e += 256) atomicAdd(&hist[dst[e] >> BSH], 1);
    __syncthreads();
    for (int i = t; i < nbkt; i += 256) cnts[(size_t)i * NCHUNK + c] = hist[i];
}

// one wave per bucket: exclusive scan over the NCHUNK chunk-counts (in place),
// bucket total -> btot[b]. cnts reads/writes are lane-coalesced.
__global__ __launch_bounds__(256) void k_chunksum(int* __restrict__ cnts,
                                                  int* __restrict__ btot, int nbkt) {
    int b = blockIdx.x * 4 + (threadIdx.x >> 6);
    if (b >= nbkt) return;
    int l = threadIdx.x & 63;
    int carry = 0;
    for (int g = 0; g < NCHUNK; g += 64) {
        int v = cnts[(size_t)b * NCHUNK + g + l];
        int x = v;
#pragma unroll
        for (int off = 1; off < 64; off <<= 1) {
            int u = __shfl_up(x, off);
            if (l >= off) x += u;
        }
        cnts[(size_t)b * NCHUNK + g + l] = carry + x - v;  // exclusive
        carry += __shfl(x, 63);
    }
    if (l == 0) btot[b] = carry;
}

// one block: exclusive scan of bucket totals -> bbase[0..nbkt] (bbase[nbkt] = E)
__global__ __launch_bounds__(MAXB) void k_bktscan(const int* __restrict__ btot,
                                                  int* __restrict__ bbase, int nbkt) {
    __shared__ int s[MAXB];
    int t = threadIdx.x;
    int v = (t < nbkt) ? btot[t] : 0;
    s[t] = v;
    __syncthreads();
    for (int off = 1; off < MAXB; off <<= 1) {
        int u = (t >= off) ? s[t - off] : 0;
        __syncthreads();
        s[t] += u;
        __syncthreads();
    }
    if (t < nbkt) bbase[t + 1] = s[t];
    if (t == 0) bbase[0] = 0;
}

// chunk c: place packed pairs at precomputed per-(chunk,bucket) offsets;
// cursors advance via LDS atomics only.
__global__ __launch_bounds__(256) void k_place(const int* __restrict__ src,
                                               const int* __restrict__ dst,
                                               const int* __restrict__ cnts,
                                               const int* __restrict__ bbase,
                                               unsigned* __restrict__ pairs,
                                               int E, int nbkt, int chunk) {
    __shared__ int cur[MAXB];
    int c = blockIdx.x;
    int t = threadIdx.x;
    for (int i = t; i < nbkt; i += 256)
        cur[i] = bbase[i] + cnts[(size_t)i * NCHUNK + c];
    __syncthreads();
    int e0 = c * chunk, e1 = min(e0 + chunk, E);
    for (int e = e0 + t; e < e1; e += 256) {
        int d = dst[e];
        int p = atomicAdd(&cur[d >> BSH], 1);
        pairs[p] = ((unsigned)(d & (BNODES - 1)) << 24) | (unsigned)src[e];
    }
}

// one block per bucket: derive per-node degree (LDS count over pairs), LDS scan
// -> rp + dinv + local cursors, then scatter col within the bucket's region.
__global__ __launch_bounds__(BNODES) void k_build(const unsigned* __restrict__ pairs,
                                                  const int* __restrict__ bbase,
                                                  int* __restrict__ rp,
                                                  float* __restrict__ dinv,
                                                  int* __restrict__ col, int N) {
    __shared__ int cntL[BNODES];
    __shared__ int lcur[BNODES];
    int b = blockIdx.x;
    int n0 = b << BSH;
    int t = threadIdx.x;
    int e0 = bbase[b], e1 = bbase[b + 1];

    cntL[t] = 0;
    __syncthreads();
    for (int e = e0 + t; e < e1; e += BNODES)
        atomicAdd(&cntL[pairs[e] >> 24], 1);
    __syncthreads();
    int deg = cntL[t];
    // inclusive scan of cntL (Hillis-Steele, in place)
    for (int off = 1; off < BNODES; off <<= 1) {
        int u = (t >= off) ? cntL[t - off] : 0;
        __syncthreads();
        cntL[t] += u;
        __syncthreads();
    }
    int rpv = e0 + cntL[t] - deg;  // exclusive + bucket base
    lcur[t] = rpv;
    int node = n0 + t;
    if (node < N) {
        rp[node] = rpv;
        dinv[node] = rsqrtf((float)deg + 1.0f);  // +1 self-loop
        if (node == N - 1) rp[N] = e1;
    }
    __syncthreads();
    for (int e = e0 + t; e < e1; e += BNODES) {
        unsigned v = pairs[e];
        int p = atomicAdd(&lcur[v >> 24], 1);
        col[p] = (int)(v & 0x00FFFFFFu);
    }
}

// ---------------- x -> bf16, pre-scaled by dinv[row] ----------------
__global__ __launch_bounds__(256) void k_cvt(const float* __restrict__ x,
                                             const float* __restrict__ dinv,
                                             unsigned short* __restrict__ y, int nchunk) {
    int g = blockIdx.x * blockDim.x + threadIdx.x;
    if (g >= nchunk) return;
    int row = g >> 5;  // 32 chunks of 4 per 128-wide row
    float s = dinv[row];
    float4 v = reinterpret_cast<const float4*>(x)[g];
    ushort4 o;
    o.x = f2bf(v.x * s);
    o.y = f2bf(v.y * s);
    o.z = f2bf(v.z * s);
    o.w = f2bf(v.w * s);
    reinterpret_cast<ushort4*>(y)[g] = o;
}

// ---------------- normalized aggregation (gather, bf16 rows) ----------------
// outp[n] (bf16 pairs) = bf16( dinv[n] * ( y[n] + sum_{e in CSR(n)} y[col[e]] ) )
// One wave64 per node; lane owns a bf16 feature pair (u32); edge loop unrolled x8.
__global__ __launch_bounds__(256) void k_agg(const unsigned short* __restrict__ y,
                                             unsigned* __restrict__ outp,
                                             const int* __restrict__ col,
                                             const int* __restrict__ rp,
                                             const float* __restrict__ dinv, int n) {
    int node = blockIdx.x * 4 + (threadIdx.x >> 6);
    if (node >= n) return;
    int c = threadIdx.x & 63;  // feature pair index
    const unsigned* yv = reinterpret_cast<const unsigned*>(y);

    unsigned v = yv[(size_t)node * 64 + c];  // self loop
    float a0 = lo_f(v), a1 = hi_f(v);

    int e0 = rp[node], e1 = rp[node + 1];
    int e = e0;
    for (; e + 8 <= e1; e += 8) {
        int s[8];
#pragma unroll
        for (int i = 0; i < 8; ++i) s[i] = col[e + i];
        unsigned u[8];
#pragma unroll
        for (int i = 0; i < 8; ++i) u[i] = yv[(size_t)s[i] * 64 + c];
#pragma unroll
        for (int i = 0; i < 8; ++i) { a0 += lo_f(u[i]); a1 += hi_f(u[i]); }
    }
    for (; e + 4 <= e1; e += 4) {
        int s0 = col[e], s1 = col[e + 1], s2 = col[e + 2], s3 = col[e + 3];
        unsigned u0 = yv[(size_t)s0 * 64 + c];
        unsigned u1 = yv[(size_t)s1 * 64 + c];
        unsigned u2 = yv[(size_t)s2 * 64 + c];
        unsigned u3 = yv[(size_t)s3 * 64 + c];
        a0 += (lo_f(u0) + lo_f(u1)) + (lo_f(u2) + lo_f(u3));
        a1 += (hi_f(u0) + hi_f(u1)) + (hi_f(u2) + hi_f(u3));
    }
    for (; e < e1; ++e) {
        unsigned u = yv[(size_t)col[e] * 64 + c];
        a0 += lo_f(u);
        a1 += hi_f(u);
    }
    float dn = dinv[node];
    unsigned o = ((unsigned)f2bf(a1 * dn) << 16) | (unsigned)f2bf(a0 * dn);
    outp[(size_t)node * 64 + c] = o;
}

// ---------------- MFMA GEMM + bias + relu (bf16 in, f32 acc) ----------------
// A [N][128] bf16 (agg output), W [128][128] f32 (converted to bf16 in LDS,
// transposed: Wt[col][k]), 256 thr = 4 waves, each wave 32 rows x 128 cols.
// STORE_BF16=1: out_bf16 = bf16(dinv[r]*relu(acc+bias)); else out_f32 = relu.
// C/D mapping (HW-verified): col = lane&15, row = (lane>>4)*4 + reg.
// A/B k-ordering assumption is consistent between operands, so any bijective
// per-slot k-map cancels in the dot product.
template <int STORE_BF16>
__global__ __launch_bounds__(256) void k_mfma(const unsigned short* __restrict__ A,
                                              const float* __restrict__ W,
                                              const float* __restrict__ bias,
                                              float* __restrict__ out_f32,
                                              unsigned short* __restrict__ out_bf16,
                                              const float* __restrict__ dinv, int N) {
    __shared__ unsigned short Wt[128][136];  // bf16 bits; padded: 272B row, 16B-aligned
    int tid = threadIdx.x;
#pragma unroll
    for (int i = 0; i < 64; ++i) {
        int idx = tid + i * 256;  // 16384 = 128*128
        int k = idx >> 7, c = idx & 127;
        Wt[c][k] = f2bf(W[idx]);
    }
    __syncthreads();

    int wv = tid >> 6, l = tid & 63;
    int lr = l & 15, lg = l >> 4;
    int r0 = blockIdx.x * 128 + wv * 32;

    f32x4 acc[2][8];
#pragma unroll
    for (int mi = 0; mi < 2; ++mi)
#pragma unroll
        for (int nf = 0; nf < 8; ++nf) acc[mi][nf] = (f32x4)(0.0f);

#pragma unroll
    for (int k0 = 0; k0 < 128; k0 += 32) {
        bf16x8 a[2];
#pragma unroll
        for (int mi = 0; mi < 2; ++mi) {
            int r = r0 + mi * 16 + lr;
            if (r >= N) r = N - 1;  // clamp: loads valid, stores guarded
            a[mi] = *reinterpret_cast<const bf16x8*>(&A[(size_t)r * 128 + k0 + lg * 8]);
        }
#pragma unroll
        for (int nf = 0; nf < 8; ++nf) {
            bf16x8 b = *reinterpret_cast<const bf16x8*>(&Wt[nf * 16 + lr][k0 + lg * 8]);
            acc[0][nf] = __builtin_amdgcn_mfma_f32_16x16x32_bf16(a[0], b, acc[0][nf], 0, 0, 0);
            acc[1][nf] = __builtin_amdgcn_mfma_f32_16x16x32_bf16(a[1], b, acc[1][nf], 0, 0, 0);
        }
    }

    float bv[8];
#pragma unroll
    for (int nf = 0; nf < 8; ++nf) bv[nf] = bias[nf * 16 + lr];

#pragma unroll
    for (int mi = 0; mi < 2; ++mi) {
#pragma unroll
        for (int q = 0; q < 4; ++q) {
            int r = r0 + mi * 16 + lg * 4 + q;
            if (r < N) {
                float dv = 1.0f;
                if (STORE_BF16) dv = dinv[r];
#pragma unroll
                for (int nf = 0; nf < 8; ++nf) {
                    int ccol = nf * 16 + lr;
                    float vv = fmaxf(acc[mi][nf][q] + bv[nf], 0.0f);
                    if (STORE_BF16)
                        out_bf16[(size_t)r * 128 + ccol] = f2bf(vv * dv);
                    else
                        out_f32[(size_t)r * 128 + ccol] = vv;
                }
            }
        }
    }
}

// ---------------- launch ----------------

extern "C" void kernel_launch(void* const* d_in, const int* in_sizes, int n_in,
                              void* d_out, int out_size, void* d_ws, size_t ws_size,
                              hipStream_t stream) {
    const float* x  = (const float*)d_in[0];
    const int*   ei = (const int*)d_in[1];
    const float* W1 = (const float*)d_in[2];
    const float* b1 = (const float*)d_in[3];
    const float* W2 = (const float*)d_in[4];
    const float* b2 = (const float*)d_in[5];
    float* out = (float*)d_out;

    const int N = in_sizes[0] / D;
    const int E = in_sizes[1] / 2;
    const int* src = ei;
    const int* dst = ei + E;
    const int NBKT = (N + BNODES - 1) >> BSH;     // 391 for N=100000 (<= MAXB)
    const int CHUNK = (E + NCHUNK - 1) / NCHUNK;  // 3125 for E=1.6M

    char* w = (char*)d_ws;
    auto alloc = [&](size_t bytes) -> void* {
        void* p = (void*)w;
        w += (bytes + 255) & ~(size_t)255;
        return p;
    };
    float* dinv     = (float*)alloc((size_t)N * 4);
    int* rp         = (int*)alloc((size_t)(N + 1) * 4);
    int* cnts       = (int*)alloc((size_t)NBKT * NCHUNK * 4);  // ~0.8 MB
    int* btot       = (int*)alloc((size_t)NBKT * 4);
    int* bbase      = (int*)alloc((size_t)(NBKT + 1) * 4);
    unsigned* pairs = (unsigned*)alloc((size_t)E * 4);
    int* col        = (int*)alloc((size_t)E * 4);
    unsigned short* y    = (unsigned short*)alloc((size_t)N * D * 2);
    unsigned short* Abuf = (unsigned short*)alloc((size_t)N * D * 2);

    k_hist<<<NCHUNK, 256, 0, stream>>>(dst, cnts, E, NBKT, CHUNK);
    k_chunksum<<<(NBKT + 3) / 4, 256, 0, stream>>>(cnts, btot, NBKT);
    k_bktscan<<<1, MAXB, 0, stream>>>(btot, bbase, NBKT);
    k_place<<<NCHUNK, 256, 0, stream>>>(src, dst, cnts, bbase, pairs, E, NBKT, CHUNK);
    k_build<<<NBKT, BNODES, 0, stream>>>(pairs, bbase, rp, dinv, col, N);

    const int nchunk = N * (D / 4);
    const int aggblocks = (N + 3) / 4;
    const int gemmblocks = (N + 127) / 128;

    // layer 1: y = bf16(dinv*x); A1 = agg(y) bf16; y = bf16(dinv*relu(A1@W1+b1))
    k_cvt<<<(nchunk + 255) / 256, 256, 0, stream>>>(x, dinv, y, nchunk);
    k_agg<<<aggblocks, 256, 0, stream>>>(y, (unsigned*)Abuf, col, rp, dinv, N);
    k_mfma<1><<<gemmblocks, 256, 0, stream>>>(Abuf, W1, b1, nullptr, y, dinv, N);
    // layer 2: A2 = agg(y) bf16; out = relu(A2@W2+b2) f32
    k_agg<<<aggblocks, 256, 0, stream>>>(y, (unsigned*)Abuf, col, rp, dinv, N);
    k_mfma<0><<<gemmblocks, 256, 0, stream>>>(Abuf, W2, b2, out, nullptr, dinv, N);
}